// Round 5
// baseline (41.410 us; speedup 1.0000x reference)
//
#include <hip/hip_runtime.h>
#include <math.h>

#define NB 30           // NUM_BINS
#define PS 99           // per-column LDS stride in floats (99 mod 32 = 3)
#define TPB 256

typedef float f32x4 __attribute__((ext_vector_type(4)));

__device__ __forceinline__ float softplus_f(float x) {
    return fmaxf(x, 0.0f) + log1pf(__expf(-fabsf(x)));
}

// softmax -> min-size floor -> cumsum for one column; writes dst[3*k], k=0..NB.
__device__ __forceinline__ void stage_cum(const float* __restrict__ u, int v,
                                          float* __restrict__ dst) {
    float r[NB];
#pragma unroll
    for (int k = 0; k < NB; ++k) r[k] = u[v * NB + k];
    float m = r[0];
#pragma unroll
    for (int k = 1; k < NB; ++k) m = fmaxf(m, r[k]);
    float s = 0.f;
#pragma unroll
    for (int k = 0; k < NB; ++k) s += __expf(r[k] - m);
    const float fac = (1.0f - 0.001f * (float)NB) / s;
    float run = 0.f;
    dst[0] = 0.f;
#pragma unroll
    for (int k = 0; k < NB; ++k) {
        run += 0.001f + fac * __expf(r[k] - m);
        dst[3 * (k + 1)] = run;
    }
}

// full param set for one column into LDS triples (cw,ch,dv) stride 3, + sentinel
__device__ __forceinline__ void col_params(const float* __restrict__ uw,
                                           const float* __restrict__ uh,
                                           const float* __restrict__ ud,
                                           int v, float* __restrict__ pcw) {
    stage_cum(uw, v, pcw);           // cumwidths  -> pc[3k]
    stage_cum(uh, v, pcw + 1);       // cumheights -> pc[3k+1]
    pcw[2] = 1.0f;                   // edge deriv == 1 exactly
    pcw[3 * NB + 2] = 1.0f;
#pragma unroll
    for (int k = 1; k < NB; ++k)
        pcw[3 * k + 2] = 0.001f + softplus_f(ud[v * (NB - 1) + k - 1]);
    pcw[93] = 3.0e38f;               // search sentinel
}

__device__ __forceinline__ void spline_eval(float cwl, float chl, float d0,
                                            float cwr, float chr, float d1,
                                            float xq, float xraw,
                                            float& o, float& ldv) {
    const float wd = cwr - cwl;
    const float h  = chr - chl;
    const float winv = __builtin_amdgcn_rcpf(wd);
    const float delta = h * winv;
    const float theta = (xq - cwl) * winv;
    const float omt = 1.0f - theta;
    const float t1mt = theta * omt;
    const float th2 = theta * theta;
    const float den = delta + (d0 + d1 - 2.0f * delta) * t1mt;
    const float dinv = __builtin_amdgcn_rcpf(den);
    const float oi = chl + h * (delta * th2 + d0 * t1mt) * dinv;
    const float numd = delta * delta * (d1 * th2 + 2.0f * delta * t1mt + d0 * omt * omt);
    const float li = __logf(numd * dinv * dinv);
    const bool inside = (xraw >= 0.0f) && (xraw <= 1.0f);
    o   = inside ? oi : xraw;        // outside: slope-1 identity
    ldv = inside ? li : 0.0f;
}

// ---- fast path: V==512, B%16==0. lane -> (4-col group, row-sub); f32x4 I/O ----
__global__ __launch_bounds__(TPB, 5) void rqs_vec_kernel(
        const float* __restrict__ x_in, const float* __restrict__ uw,
        const float* __restrict__ uh, const float* __restrict__ ud,
        float* __restrict__ out, float* __restrict__ lad,
        int B, int rowTiles) {
    const int V = 512;
    __shared__ float pkS[64 * PS];

    const int tid = threadIdx.x;
    const int colTile = blockIdx.x & 7;            // nct = 8
    const int rowBlk  = blockIdx.x >> 3;
    const int colbase = colTile * 64;

    if (tid < 64) col_params(uw, uh, ud, colbase + tid, &pkS[tid * PS]);
    __syncthreads();

    const int l = tid & 63;
    const int w = tid >> 6;                        // wave 0..3
    const int g = (l & 15) * 4;                    // first column of group
    const int r = l >> 4;                          // row-sub 0..3
    const int col0 = colbase + g;
    const float* __restrict__ pg = &pkS[g * PS];

    // hoist search levels 1-3 boundaries (7 per column x 4 columns)
    float hb[4][7];
#pragma unroll
    for (int i = 0; i < 4; ++i)
#pragma unroll
        for (int t = 0; t < 7; ++t) hb[i][t] = pg[i * PS + 12 * (t + 1)];

    const int rowStep = rowTiles * 16;
    int row = rowBlk * 16 + w * 4 + r;
    if (row >= B) return;
    f32x4 xcur = *(const f32x4*)(x_in + (size_t)row * V + col0);

    while (true) {
        const int nrow = row + rowStep;
        const bool has = (nrow < B);               // wave-uniform (B%16==0)
        f32x4 xnext;
        if (has) xnext = *(const f32x4*)(x_in + (size_t)nrow * V + col0);

        float xq[4];
        int jj[4];
#pragma unroll
        for (int i = 0; i < 4; ++i) xq[i] = fminf(fmaxf(xcur[i], 0.0f), 1.0f);

        // levels 1-3: register cndmask tree
#pragma unroll
        for (int i = 0; i < 4; ++i) {
            const bool b1 = hb[i][3] <= xq[i];
            const float l2 = b1 ? hb[i][5] : hb[i][1];
            const bool b2 = l2 <= xq[i];
            const float l3 = b1 ? (b2 ? hb[i][6] : hb[i][4])
                               : (b2 ? hb[i][2] : hb[i][0]);
            const bool b3 = l3 <= xq[i];
            jj[i] = (b1 ? 48 : 0) + (b2 ? 24 : 0) + (b3 ? 12 : 0);
        }
        // levels 4-5: two dependent LDS reads, 4 chains in flight
#pragma unroll
        for (int i = 0; i < 4; ++i) jj[i] += (pg[i * PS + jj[i] + 6] <= xq[i]) ? 6 : 0;
#pragma unroll
        for (int i = 0; i < 4; ++i) jj[i] += (pg[i * PS + jj[i] + 3] <= xq[i]) ? 3 : 0;
#pragma unroll
        for (int i = 0; i < 4; ++i) jj[i] = min(jj[i], 87) + i * PS;

        float cwl[4], chl[4], d0a[4], cwr[4], chr[4], d1a[4];
#pragma unroll
        for (int i = 0; i < 4; ++i) {
            const float* p = pg + jj[i];
            cwl[i] = p[0]; chl[i] = p[1]; d0a[i] = p[2];   // 3x ds_read2_b32
            cwr[i] = p[3]; chr[i] = p[4]; d1a[i] = p[5];
        }

        f32x4 o, ldv;
#pragma unroll
        for (int i = 0; i < 4; ++i) {
            float oi, li;
            spline_eval(cwl[i], chl[i], d0a[i], cwr[i], chr[i], d1a[i],
                        xq[i], xcur[i], oi, li);
            o[i] = oi;
            ldv[i] = li;
        }

        *(f32x4*)(out + (size_t)row * V + col0) = o;
        *(f32x4*)(lad + (size_t)row * V + col0) = ldv;

        if (!has) break;
        row = nrow;
        xcur = xnext;
    }
}

// ---- generic fallback: any V, any B (scalar access, per-element guards) ----
__global__ __launch_bounds__(TPB, 4) void rqs_gen_kernel(
        const float* __restrict__ x_in, const float* __restrict__ uw,
        const float* __restrict__ uh, const float* __restrict__ ud,
        float* __restrict__ out, float* __restrict__ lad,
        int B, int V, int nct, int rowTiles) {
    __shared__ float pkS[64 * PS];

    const int tid = threadIdx.x;
    const int colTile = blockIdx.x % nct;
    const int rowBlk  = blockIdx.x / nct;
    const int colbase = colTile * 64;

    if (tid < 64 && colbase + tid < V)
        col_params(uw, uh, ud, colbase + tid, &pkS[tid * PS]);
    __syncthreads();

    const int c = tid & 63;
    const int w = tid >> 6;
    const int col = colbase + c;
    if (col >= V) return;
    const float* __restrict__ pc = &pkS[c * PS];

    for (int row = rowBlk * 4 + w; row < B; row += rowTiles * 4) {
        const float xr = x_in[(size_t)row * V + col];
        const float xq = fminf(fmaxf(xr, 0.0f), 1.0f);
        int j = (pc[48] <= xq) ? 48 : 0;
        j += (pc[j + 24] <= xq) ? 24 : 0;
        j += (pc[j + 12] <= xq) ? 12 : 0;
        j += (pc[j +  6] <= xq) ?  6 : 0;
        j += (pc[j +  3] <= xq) ?  3 : 0;
        j = min(j, 87);
        const float* p = pc + j;
        float o, ldv;
        spline_eval(p[0], p[1], p[2], p[3], p[4], p[5], xq, xr, o, ldv);
        out[(size_t)row * V + col] = o;
        lad[(size_t)row * V + col] = ldv;
    }
}

extern "C" void kernel_launch(void* const* d_in, const int* in_sizes, int n_in,
                              void* d_out, int out_size, void* d_ws, size_t ws_size,
                              hipStream_t stream) {
    const float* x  = (const float*)d_in[0];
    const float* uw = (const float*)d_in[1];
    const float* uh = (const float*)d_in[2];
    const float* ud = (const float*)d_in[3];

    const int V = in_sizes[1] / NB;          // 512
    const int B = in_sizes[0] / V;           // 16384

    float* out = (float*)d_out;
    float* lad = out + (size_t)B * V;

    if (V == 512 && (B % 16) == 0 && B >= 16) {
        const int rowTiles = 160;            // 8 col-tiles x 160 = 1280 blocks = 5/CU
        rqs_vec_kernel<<<8 * rowTiles, TPB, 0, stream>>>(
            x, uw, uh, ud, out, lad, B, rowTiles);
    } else {
        const int nct = (V + 63) / 64;
        int rowTiles = (B + 3) / 4;
        if (rowTiles > 128) rowTiles = 128;
        rqs_gen_kernel<<<nct * rowTiles, TPB, 0, stream>>>(
            x, uw, uh, ud, out, lad, B, V, nct, rowTiles);
    }
}